// Round 3
// baseline (638.168 us; speedup 1.0000x reference)
//
#include <hip/hip_runtime.h>
#include <math.h>

#define NB   16
#define NPTS 2048
#define KNBR 20
#define NCH  8            // knn chunks per query
#define CHSZ (NPTS/NCH)   // 256
#define NROWS (NB*NPTS)          // 32768
#define CONV_M ((double)(NB)*(double)(NPTS)*(double)(KNBR))
#define ROW_M  ((double)NROWS)
#define BN_EPS 1e-5
#define LSLOPE 0.2f

__device__ __forceinline__ float lrelu(float v) { return v >= 0.f ? v : LSLOPE * v; }

// pair-insert of (d0,d1) into sorted-desc bestv[20]; 3 ops/position via max/med3/min
__device__ __forceinline__ void pair_insert(float (&bestv)[KNBR], float d0, float d1)
{
    float t0 = fmaxf(d0, d1), t1 = fminf(d0, d1);
    if (t0 > bestv[KNBR-1]) {
#pragma unroll
        for (int j = 0; j < KNBR; ++j) {
            float bj = bestv[j];
            float nb  = fmaxf(bj, t0);
            float nt0 = __builtin_amdgcn_fmed3f(bj, t0, t1);
            float nt1 = fminf(bj, t1);
            bestv[j] = nb;
            t0 = nt0; t1 = nt1;
        }
    }
}

__device__ __forceinline__ float dist_eval(float4 q, float4 pm)
{
    float inner = __fadd_rn(__fadd_rn(__fmul_rn(q.x,pm.x), __fmul_rn(q.y,pm.y)), __fmul_rn(q.z,pm.z));
    return __fsub_rn(__fsub_rn(__fmul_rn(2.0f, inner), q.w), pm.w);
}

// ---------------------------------------------------------------------------
// KNN pass A: per (query, chunk-of-256) thread, exact top-20 values of chunk.
// ---------------------------------------------------------------------------
__global__ __launch_bounds__(256) void knn_part(const float* __restrict__ x,
                                                float* __restrict__ P)
{
    __shared__ float4 cpt[CHSZ];
    __shared__ float4 qpt[256];
    const int b  = blockIdx.x >> 6;
    const int qg = (blockIdx.x >> 3) & 7;
    const int c  = blockIdx.x & 7;
    const float* xb = x + (size_t)b * NPTS * 3;
    {
        int j = c * CHSZ + threadIdx.x;
        float px = xb[j*3+0], py = xb[j*3+1], pz = xb[j*3+2];
        float xx = __fadd_rn(__fadd_rn(__fmul_rn(px,px), __fmul_rn(py,py)), __fmul_rn(pz,pz));
        cpt[threadIdx.x] = make_float4(px, py, pz, xx);
        int n = qg * 256 + threadIdx.x;
        px = xb[n*3+0]; py = xb[n*3+1]; pz = xb[n*3+2];
        xx = __fadd_rn(__fadd_rn(__fmul_rn(px,px), __fmul_rn(py,py)), __fmul_rn(pz,pz));
        qpt[threadIdx.x] = make_float4(px, py, pz, xx);
    }
    __syncthreads();
    const float4 q = qpt[threadIdx.x];
    float bestv[KNBR];
#pragma unroll
    for (int j = 0; j < KNBR; ++j) bestv[j] = -__builtin_inff();
    for (int m = 0; m < CHSZ; m += 2) {
        float d0 = dist_eval(q, cpt[m]);
        float d1 = dist_eval(q, cpt[m+1]);
        pair_insert(bestv, d0, d1);
    }
    const size_t bq = (size_t)b * NPTS + qg * 256 + threadIdx.x;
#pragma unroll
    for (int i = 0; i < KNBR; ++i)
        P[(size_t)(c * KNBR + i) * NROWS + bq] = bestv[i];
}

// ---------------------------------------------------------------------------
// KNN pass B: merge 8 sorted top-20 lists per query -> exact 20th-largest value
// ---------------------------------------------------------------------------
__global__ __launch_bounds__(256) void knn_merge(const float* __restrict__ P,
                                                 float* __restrict__ thresh)
{
    const size_t bq = (size_t)blockIdx.x * 256 + threadIdx.x;
    float bestv[KNBR];
#pragma unroll
    for (int j = 0; j < KNBR; ++j) bestv[j] = -__builtin_inff();
    for (int c = 0; c < NCH; ++c)
#pragma unroll
        for (int i = 0; i < KNBR; i += 2) {
            float d0 = P[(size_t)(c * KNBR + i)     * NROWS + bq];
            float d1 = P[(size_t)(c * KNBR + i + 1) * NROWS + bq];
            pair_insert(bestv, d0, d1);
        }
    thresh[bq] = bestv[KNBR-1];
}

// ---------------------------------------------------------------------------
// KNN pass C: index recovery (tie-exact, ascending m).
// ---------------------------------------------------------------------------
__global__ __launch_bounds__(256) void knn_idx(const float* __restrict__ x,
        const float* __restrict__ thresh, int* __restrict__ idxo)
{
    __shared__ float4 pts[NPTS];
    __shared__ unsigned char hitb[32][NCH][KNBR];
    __shared__ int cnts[32][NCH];
    const int b  = blockIdx.x >> 6;
    const int qg = blockIdx.x & 63;
    const float* xb = x + (size_t)b * NPTS * 3;
    for (int i = threadIdx.x; i < NPTS; i += 256) {
        float px = xb[i*3+0], py = xb[i*3+1], pz = xb[i*3+2];
        float xx = __fadd_rn(__fadd_rn(__fmul_rn(px,px), __fmul_rn(py,py)), __fmul_rn(pz,pz));
        pts[i] = make_float4(px, py, pz, xx);
    }
    __syncthreads();
    const int qi = threadIdx.x >> 3;
    const int sp = threadIdx.x & 7;
    const int n  = qg * 32 + qi;
    const float4 q = pts[n];
    const float th = thresh[(size_t)b * NPTS + n];
    int lc = 0;
    const int j0 = sp * CHSZ;
    for (int j = j0; j < j0 + CHSZ; ++j) {
        float d = dist_eval(q, pts[j]);
        if (d >= th) { if (lc < KNBR) hitb[qi][sp][lc] = (unsigned char)(j - j0); ++lc; }
    }
    cnts[qi][sp] = lc < KNBR ? lc : KNBR;
    __syncthreads();
    int base = 0;
    for (int s = 0; s < sp; ++s) base += cnts[qi][s];
    int* op = idxo + ((size_t)b * NPTS + n) * KNBR;
    const int lim = cnts[qi][sp];
    for (int l = 0; l < lim; ++l) {
        int r = base + l;
        if (r < KNBR) op[r] = j0 + (int)hitb[qi][sp][l];
    }
}

// ---------------------------------------------------------------------------
// Edge-conv + factored BN-stat moments (unchanged)
// ---------------------------------------------------------------------------
__global__ __launch_bounds__(256) void feat_kernel(const float* __restrict__ x,
        const int* __restrict__ idx, const float* __restrict__ conv_w,
        float* __restrict__ maxh, float* __restrict__ minh, double* __restrict__ S)
{
    __shared__ float  featw[4][KNBR][6];
    __shared__ double sred[4][27];
    const int wv = threadIdx.x >> 6, lane = threadIdx.x & 63;
    float cw[6];
#pragma unroll
    for (int c = 0; c < 6; ++c) cw[c] = conv_w[lane*6 + c];
    int pa_ = 0, pb_ = 0;
    if (lane >= 6 && lane < 27) {
        int t = lane - 6, a = 0;
        while (t >= 6 - a) { t -= 6 - a; ++a; }
        pa_ = a; pb_ = a + t;
    }
    double acc = 0.0;
    for (int i = 0; i < 8; ++i) {
        const int bp = blockIdx.x * 32 + wv * 8 + i;
        const int b = bp >> 11, n = bp & (NPTS - 1);
        const float* xb = x + (size_t)b * NPTS * 3;
        const float xi0 = xb[n*3+0], xi1 = xb[n*3+1], xi2 = xb[n*3+2];
        float f0=0,f1=0,f2=0,f3=0,f4=0,f5=0;
        if (lane < KNBR) {
            const int nj = idx[(size_t)bp * KNBR + lane];
            f0 = xb[nj*3+0] - xi0; f1 = xb[nj*3+1] - xi1; f2 = xb[nj*3+2] - xi2;
            f3 = xi0; f4 = xi1; f5 = xi2;
        }
        __syncthreads();
        if (lane < KNBR) {
            featw[wv][lane][0]=f0; featw[wv][lane][1]=f1; featw[wv][lane][2]=f2;
            featw[wv][lane][3]=f3; featw[wv][lane][4]=f4; featw[wv][lane][5]=f5;
        }
        __syncthreads();
        float vmax = -__builtin_inff(), vmin = __builtin_inff();
#pragma unroll
        for (int k = 0; k < KNBR; ++k) {
            float h = featw[wv][k][0] * cw[0];
            h = fmaf(featw[wv][k][1], cw[1], h);
            h = fmaf(featw[wv][k][2], cw[2], h);
            h = fmaf(featw[wv][k][3], cw[3], h);
            h = fmaf(featw[wv][k][4], cw[4], h);
            h = fmaf(featw[wv][k][5], cw[5], h);
            vmax = fmaxf(vmax, h); vmin = fminf(vmin, h);
        }
        maxh[(size_t)bp*64 + lane] = vmax;
        minh[(size_t)bp*64 + lane] = vmin;
        if (lane < 6) {
            double s = 0;
#pragma unroll
            for (int k = 0; k < KNBR; ++k) s += (double)featw[wv][k][lane];
            acc += s;
        } else if (lane < 27) {
            double s = 0;
#pragma unroll
            for (int k = 0; k < KNBR; ++k)
                s += (double)featw[wv][k][pa_] * (double)featw[wv][k][pb_];
            acc += s;
        }
    }
    if (lane < 27) sred[wv][lane] = acc;
    __syncthreads();
    if (threadIdx.x < 27) {
        double tot = sred[0][threadIdx.x] + sred[1][threadIdx.x]
                   + sred[2][threadIdx.x] + sred[3][threadIdx.x];
        atomicAdd(&S[threadIdx.x], tot);
    }
}

__global__ void stats0_kernel(const double* __restrict__ S, const float* __restrict__ conv_w,
        const float* __restrict__ g, const float* __restrict__ bb,
        float* __restrict__ scale, float* __restrict__ shift)
{
    const int o = threadIdx.x;
    double w[6];
#pragma unroll
    for (int c = 0; c < 6; ++c) w[c] = (double)conv_w[o*6 + c];
    double mean = 0.0;
#pragma unroll
    for (int c = 0; c < 6; ++c) mean += w[c] * S[c];
    mean /= CONV_M;
    double ey2 = 0.0;
    int t = 6;
#pragma unroll
    for (int a = 0; a < 6; ++a)
#pragma unroll
        for (int b2 = a; b2 < 6; ++b2) {
            double coef = (a == b2) ? 1.0 : 2.0;
            ey2 += coef * w[a] * w[b2] * S[t];
            ++t;
        }
    ey2 /= CONV_M;
    double var = ey2 - mean * mean;
    double sc = (double)g[o] / sqrt(var + BN_EPS);
    scale[o] = (float)sc;
    shift[o] = (float)((double)bb[o] - mean * sc);
}

__global__ void statsL_kernel(const double* __restrict__ sum, const double* __restrict__ sq,
        const float* __restrict__ g, const float* __restrict__ bt,
        float* __restrict__ scale, float* __restrict__ shift, int C)
{
    const int o = threadIdx.x;
    if (o >= C) return;
    double m = sum[o] / ROW_M;
    double v = sq[o] / ROW_M - m * m;
    double sc = (double)g[o] / sqrt(v + BN_EPS);
    scale[o] = (float)sc;
    shift[o] = (float)((double)bt[o] - m * sc);
}

// ---------------------------------------------------------------------------
// MLP layer: lane = row, 32-output tile per thread, weights via wave-uniform
// s_load (zero VALU cost), 32 independent FMA chains. BN+lrelu fused on load.
// Accumulation order (bias, c ascending) identical to previous rounds.
// ---------------------------------------------------------------------------
template<int K, int N, bool SEL>
__global__ __launch_bounds__(256) void mlp_kernel(const float* __restrict__ A,
        const float* __restrict__ A2, const float* __restrict__ sc_,
        const float* __restrict__ sh_, const float* __restrict__ W,
        const float* __restrict__ bias, float* __restrict__ Y)
{
    const int r  = blockIdx.x * 256 + threadIdx.x;
    const int ot = blockIdx.y * 32;
    float acc[32];
#pragma unroll
    for (int i = 0; i < 32; ++i) acc[i] = bias[ot + i];
#pragma unroll
    for (int cc = 0; cc < K; cc += 32) {
        float a[32];
#pragma unroll
        for (int v = 0; v < 8; ++v) {
            const int c0 = cc + v*4;
            float4 m = *(const float4*)(A + (size_t)r*K + c0);
            if (SEL) {
                float4 m2 = *(const float4*)(A2 + (size_t)r*K + c0);
                m.x = sc_[c0+0] >= 0.f ? m.x : m2.x;
                m.y = sc_[c0+1] >= 0.f ? m.y : m2.y;
                m.z = sc_[c0+2] >= 0.f ? m.z : m2.z;
                m.w = sc_[c0+3] >= 0.f ? m.w : m2.w;
            }
            a[v*4+0] = lrelu(fmaf(sc_[c0+0], m.x, sh_[c0+0]));
            a[v*4+1] = lrelu(fmaf(sc_[c0+1], m.y, sh_[c0+1]));
            a[v*4+2] = lrelu(fmaf(sc_[c0+2], m.z, sh_[c0+2]));
            a[v*4+3] = lrelu(fmaf(sc_[c0+3], m.w, sh_[c0+3]));
        }
#pragma unroll
        for (int c = 0; c < 32; ++c)
#pragma unroll
            for (int i = 0; i < 32; ++i)
                acc[i] = fmaf(a[c], W[(size_t)(cc + c)*N + ot + i], acc[i]);
    }
    float4* yo = (float4*)(Y + (size_t)r*N + ot);
#pragma unroll
    for (int v = 0; v < 8; ++v)
        yo[v] = make_float4(acc[v*4+0], acc[v*4+1], acc[v*4+2], acc[v*4+3]);
}

// ---------------------------------------------------------------------------
// Column stats: per-channel sum / sumsq of Y (coalesced; f32 block partials,
// 64 double atomics per channel).
// ---------------------------------------------------------------------------
template<int N>
__global__ __launch_bounds__(256) void colstats_kernel(const float* __restrict__ Y,
        double* __restrict__ sum, double* __restrict__ sq)
{
    constexpr int RPB  = 256 / N;        // rows covered by a block per step
    constexpr int RSTR = 64 * RPB;       // row stride (64 blocks)
    const int ch   = threadIdx.x & (N - 1);
    const int rsub = threadIdx.x / N;
    float s = 0.f, q = 0.f;
    for (int r = blockIdx.x * RPB + rsub; r < NROWS; r += RSTR) {
        float v = Y[(size_t)r * N + ch];
        s += v; q = fmaf(v, v, q);
    }
    __shared__ float ls[256], lq[256];
    ls[threadIdx.x] = s; lq[threadIdx.x] = q;
    __syncthreads();
    if (threadIdx.x < N) {
        float ss = 0.f, qq = 0.f;
#pragma unroll
        for (int k = 0; k < RPB; ++k) { ss += ls[threadIdx.x + k*N]; qq += lq[threadIdx.x + k*N]; }
        atomicAdd(&sum[threadIdx.x], (double)ss);
        atomicAdd(&sq[threadIdx.x], (double)qq);
    }
}

// pool stage 1: max over 128-point slab with BN+lrelu inline
__global__ __launch_bounds__(256) void pool1_kernel(const float* __restrict__ y3,
        const float* __restrict__ s3, const float* __restrict__ t3, float* __restrict__ pp)
{
    const int b = blockIdx.x >> 4, ns = blockIdx.x & 15;
    const int wv = threadIdx.x >> 6, lane = threadIdx.x & 63;
    const int ch = (wv & 1) * 64 + lane;
    const float sc = s3[ch], sh = t3[ch];
    float m = -__builtin_inff();
    const int n0 = ns * 128 + (wv >> 1) * 64;
    for (int n = n0; n < n0 + 64; ++n) {
        float v = lrelu(fmaf(sc, y3[((size_t)b*NPTS + n)*128 + ch], sh));
        m = fmaxf(m, v);
    }
    __shared__ float red[2][128];
    red[wv >> 1][ch] = m;
    __syncthreads();
    if (threadIdx.x < 128)
        pp[((size_t)b*16 + ns)*128 + threadIdx.x] = fmaxf(red[0][threadIdx.x], red[1][threadIdx.x]);
}

__global__ void pool2_kernel(const float* __restrict__ pp, float* __restrict__ pooled)
{
    const int b = blockIdx.x, ch = threadIdx.x;
    float m = -__builtin_inff();
    for (int ns = 0; ns < 16; ++ns)
        m = fmaxf(m, pp[((size_t)b*16 + ns)*128 + ch]);
    pooled[b*128 + ch] = m;
}

__global__ __launch_bounds__(256) void head_kernel(const float* __restrict__ pooled,
        const float* __restrict__ w4, const float* __restrict__ b4,
        const float* __restrict__ w5, const float* __restrict__ b5, float* __restrict__ out)
{
    __shared__ float xr[128];
    __shared__ float hh[512];
    const int b = blockIdx.x, t = threadIdx.x;
    if (t < 128) xr[t] = pooled[b*128 + t];
    __syncthreads();
    float h0 = b4[t], h1 = b4[t + 256];
    for (int c = 0; c < 128; ++c) {
        float xc = xr[c];
        h0 = fmaf(xc, w4[c*512 + t],       h0);
        h1 = fmaf(xc, w4[c*512 + t + 256], h1);
    }
    hh[t]       = lrelu(h0);
    hh[t + 256] = lrelu(h1);
    __syncthreads();
    float acc = b5[t];
    for (int c = 0; c < 512; ++c)
        acc = fmaf(hh[c], w5[c*256 + t], acc);
    out[b*256 + t] = acc;
}

extern "C" void kernel_launch(void* const* d_in, const int* in_sizes, int n_in,
                              void* d_out, int out_size, void* d_ws, size_t ws_size,
                              hipStream_t stream)
{
    const float* x      = (const float*)d_in[0];
    const float* conv_w = (const float*)d_in[1];
    const float* conv_g = (const float*)d_in[2];
    const float* conv_b = (const float*)d_in[3];
    const float* w1  = (const float*)d_in[4];
    const float* b1  = (const float*)d_in[5];
    const float* g1  = (const float*)d_in[6];
    const float* bt1 = (const float*)d_in[7];
    const float* w2  = (const float*)d_in[8];
    const float* b2  = (const float*)d_in[9];
    const float* g2  = (const float*)d_in[10];
    const float* bt2 = (const float*)d_in[11];
    const float* w3  = (const float*)d_in[12];
    const float* b3  = (const float*)d_in[13];
    const float* g3  = (const float*)d_in[14];
    const float* bt3 = (const float*)d_in[15];
    const float* w4  = (const float*)d_in[16];
    const float* b4  = (const float*)d_in[17];
    const float* w5  = (const float*)d_in[18];
    const float* b5  = (const float*)d_in[19];

    char* p = (char*)d_ws;
    auto take = [&](size_t bytes) -> char* {
        char* r = p; p += (bytes + 255) & ~(size_t)255; return r;
    };
    double* S    = (double*)take(27 * 8);
    double* sum1 = (double*)take(64 * 8);
    double* sq1  = (double*)take(64 * 8);
    double* sum2 = (double*)take(128 * 8);
    double* sq2  = (double*)take(128 * 8);
    double* sum3 = (double*)take(128 * 8);
    double* sq3  = (double*)take(128 * 8);
    size_t zero_bytes = (size_t)(p - (char*)d_ws);
    float* scale0 = (float*)take(64 * 4);
    float* shift0 = (float*)take(64 * 4);
    float* scale1 = (float*)take(64 * 4);
    float* shift1 = (float*)take(64 * 4);
    float* scale2 = (float*)take(128 * 4);
    float* shift2 = (float*)take(128 * 4);
    float* scale3 = (float*)take(128 * 4);
    float* shift3 = (float*)take(128 * 4);
    float* pooled = (float*)take(NB * 128 * 4);
    float* pp     = (float*)take((size_t)NB * 16 * 128 * 4);
    float* thresh = (float*)take((size_t)NROWS * 4);
    int*   idx    = (int*)take((size_t)NROWS * KNBR * 4);
    float* mm     = (float*)take((size_t)NROWS * 128 * 4);
    float* maxh   = mm;
    float* minh   = mm + (size_t)NROWS * 64;
    float* y1     = (float*)take((size_t)NROWS * 64 * 4);
    float* y2     = (float*)take((size_t)NROWS * 128 * 4);
    float* y3     = mm;          // alias (maxh/minh dead after l1)
    float* P      = mm;          // alias: knn partials, dead before feat

    hipMemsetAsync(d_ws, 0, zero_bytes, stream);
    knn_part  <<<dim3(NB * 8 * NCH), dim3(256), 0, stream>>>(x, P);
    knn_merge <<<dim3(NROWS / 256),  dim3(256), 0, stream>>>(P, thresh);
    knn_idx   <<<dim3(NB * 64),      dim3(256), 0, stream>>>(x, thresh, idx);
    feat_kernel <<<dim3(NROWS / 32), dim3(256), 0, stream>>>(x, idx, conv_w, maxh, minh, S);
    stats0_kernel<<<dim3(1),         dim3(64),  0, stream>>>(S, conv_w, conv_g, conv_b, scale0, shift0);

    mlp_kernel<64,64,true>  <<<dim3(128,2), dim3(256), 0, stream>>>(maxh, minh, scale0, shift0, w1, b1, y1);
    colstats_kernel<64>     <<<dim3(64),    dim3(256), 0, stream>>>(y1, sum1, sq1);
    statsL_kernel           <<<dim3(1),     dim3(64),  0, stream>>>(sum1, sq1, g1, bt1, scale1, shift1, 64);

    mlp_kernel<64,128,false><<<dim3(128,4), dim3(256), 0, stream>>>(y1, y1, scale1, shift1, w2, b2, y2);
    colstats_kernel<128>    <<<dim3(64),    dim3(256), 0, stream>>>(y2, sum2, sq2);
    statsL_kernel           <<<dim3(1),     dim3(128), 0, stream>>>(sum2, sq2, g2, bt2, scale2, shift2, 128);

    mlp_kernel<128,128,false><<<dim3(128,4), dim3(256), 0, stream>>>(y2, y2, scale2, shift2, w3, b3, y3);
    colstats_kernel<128>    <<<dim3(64),    dim3(256), 0, stream>>>(y3, sum3, sq3);
    statsL_kernel           <<<dim3(1),     dim3(128), 0, stream>>>(sum3, sq3, g3, bt3, scale3, shift3, 128);

    pool1_kernel<<<dim3(NB * 16),    dim3(256), 0, stream>>>(y3, scale3, shift3, pp);
    pool2_kernel<<<dim3(NB),         dim3(128), 0, stream>>>(pp, pooled);
    head_kernel <<<dim3(NB),         dim3(256), 0, stream>>>(pooled, w4, b4, w5, b5, (float*)d_out);
}

// Round 4
// 432.835 us; speedup vs baseline: 1.4744x; 1.4744x over previous
//
#include <hip/hip_runtime.h>
#include <math.h>

#define NB   16
#define NPTS 2048
#define KNBR 20
#define NCH  16           // knn chunks per query (pass A)
#define CHSZ (NPTS/NCH)   // 128
#define IDXSP 8           // knn_idx splits
#define IDXSZ (NPTS/IDXSP)
#define NROWS (NB*NPTS)          // 32768
#define CONV_M ((double)(NB)*(double)(NPTS)*(double)(KNBR))
#define ROW_M  ((double)NROWS)
#define BN_EPS 1e-5
#define LSLOPE 0.2f

__device__ __forceinline__ float lrelu(float v) { return v >= 0.f ? v : LSLOPE * v; }

// unconditional pair-insert of (d0,d1) into sorted-desc bestv[20]
__device__ __forceinline__ void pair_insert(float (&bestv)[KNBR], float d0, float d1)
{
    float t0 = fmaxf(d0, d1), t1 = fminf(d0, d1);
#pragma unroll
    for (int j = 0; j < KNBR; ++j) {
        float bj = bestv[j];
        float nb  = fmaxf(bj, t0);
        float nt0 = __builtin_amdgcn_fmed3f(bj, t0, t1);
        float nt1 = fminf(bj, t1);
        bestv[j] = nb;
        t0 = nt0; t1 = nt1;
    }
}

__device__ __forceinline__ float dist_eval(float4 q, float4 pm)
{
    float inner = __fadd_rn(__fadd_rn(__fmul_rn(q.x,pm.x), __fmul_rn(q.y,pm.y)), __fmul_rn(q.z,pm.z));
    return __fsub_rn(__fsub_rn(__fmul_rn(2.0f, inner), q.w), pm.w);
}

// ---------------------------------------------------------------------------
// KNN pass A: per (query, chunk-of-128) thread, exact top-20 values of chunk.
// ---------------------------------------------------------------------------
__global__ __launch_bounds__(256) void knn_part(const float* __restrict__ x,
                                                float* __restrict__ P)
{
    __shared__ float4 cpt[CHSZ];
    __shared__ float4 qpt[256];
    const int b  = blockIdx.x >> 7;
    const int qg = (blockIdx.x >> 4) & 7;
    const int c  = blockIdx.x & 15;
    const float* xb = x + (size_t)b * NPTS * 3;
    if (threadIdx.x < CHSZ) {
        int j = c * CHSZ + threadIdx.x;
        float px = xb[j*3+0], py = xb[j*3+1], pz = xb[j*3+2];
        float xx = __fadd_rn(__fadd_rn(__fmul_rn(px,px), __fmul_rn(py,py)), __fmul_rn(pz,pz));
        cpt[threadIdx.x] = make_float4(px, py, pz, xx);
    }
    {
        int n = qg * 256 + threadIdx.x;
        float px = xb[n*3+0], py = xb[n*3+1], pz = xb[n*3+2];
        float xx = __fadd_rn(__fadd_rn(__fmul_rn(px,px), __fmul_rn(py,py)), __fmul_rn(pz,pz));
        qpt[threadIdx.x] = make_float4(px, py, pz, xx);
    }
    __syncthreads();
    const float4 q = qpt[threadIdx.x];
    float bestv[KNBR];
#pragma unroll
    for (int j = 0; j < KNBR; ++j) bestv[j] = -__builtin_inff();
    for (int m = 0; m < CHSZ; m += 2) {
        float d0 = dist_eval(q, cpt[m]);
        float d1 = dist_eval(q, cpt[m+1]);
        pair_insert(bestv, d0, d1);
    }
    const size_t bq = (size_t)b * NPTS + qg * 256 + threadIdx.x;
#pragma unroll
    for (int i = 0; i < KNBR; ++i)
        P[(size_t)(c * KNBR + i) * NROWS + bq] = bestv[i];
}

// ---------------------------------------------------------------------------
// KNN pass B: merge 16 sorted top-20 lists per query -> exact 20th-largest
// ---------------------------------------------------------------------------
__global__ __launch_bounds__(256) void knn_merge(const float* __restrict__ P,
                                                 float* __restrict__ thresh)
{
    const size_t bq = (size_t)blockIdx.x * 256 + threadIdx.x;
    float bestv[KNBR];
#pragma unroll
    for (int j = 0; j < KNBR; ++j) bestv[j] = -__builtin_inff();
    for (int c = 0; c < NCH; ++c)
#pragma unroll
        for (int i = 0; i < KNBR; i += 2) {
            float d0 = P[(size_t)(c * KNBR + i)     * NROWS + bq];
            float d1 = P[(size_t)(c * KNBR + i + 1) * NROWS + bq];
            pair_insert(bestv, d0, d1);
        }
    thresh[bq] = bestv[KNBR-1];
}

// ---------------------------------------------------------------------------
// KNN pass C: index recovery (tie-exact, ascending m).
// ---------------------------------------------------------------------------
__global__ __launch_bounds__(256) void knn_idx(const float* __restrict__ x,
        const float* __restrict__ thresh, int* __restrict__ idxo)
{
    __shared__ float4 pts[NPTS];
    __shared__ unsigned char hitb[32][IDXSP][KNBR];
    __shared__ int cnts[32][IDXSP];
    const int b  = blockIdx.x >> 6;
    const int qg = blockIdx.x & 63;
    const float* xb = x + (size_t)b * NPTS * 3;
    for (int i = threadIdx.x; i < NPTS; i += 256) {
        float px = xb[i*3+0], py = xb[i*3+1], pz = xb[i*3+2];
        float xx = __fadd_rn(__fadd_rn(__fmul_rn(px,px), __fmul_rn(py,py)), __fmul_rn(pz,pz));
        pts[i] = make_float4(px, py, pz, xx);
    }
    __syncthreads();
    const int qi = threadIdx.x >> 3;
    const int sp = threadIdx.x & 7;
    const int n  = qg * 32 + qi;
    const float4 q = pts[n];
    const float th = thresh[(size_t)b * NPTS + n];
    int lc = 0;
    const int j0 = sp * IDXSZ;
    for (int j = j0; j < j0 + IDXSZ; ++j) {
        float d = dist_eval(q, pts[j]);
        if (d >= th) { if (lc < KNBR) hitb[qi][sp][lc] = (unsigned char)(j - j0); ++lc; }
    }
    cnts[qi][sp] = lc < KNBR ? lc : KNBR;
    __syncthreads();
    int base = 0;
    for (int s = 0; s < sp; ++s) base += cnts[qi][s];
    int* op = idxo + ((size_t)b * NPTS + n) * KNBR;
    const int lim = cnts[qi][sp];
    for (int l = 0; l < lim; ++l) {
        int r = base + l;
        if (r < KNBR) op[r] = j0 + (int)hitb[qi][sp][l];
    }
}

// ---------------------------------------------------------------------------
// Edge-conv + factored BN-stat moments (unchanged)
// ---------------------------------------------------------------------------
__global__ __launch_bounds__(256) void feat_kernel(const float* __restrict__ x,
        const int* __restrict__ idx, const float* __restrict__ conv_w,
        float* __restrict__ maxh, float* __restrict__ minh, double* __restrict__ S)
{
    __shared__ float  featw[4][KNBR][6];
    __shared__ double sred[4][27];
    const int wv = threadIdx.x >> 6, lane = threadIdx.x & 63;
    float cw[6];
#pragma unroll
    for (int c = 0; c < 6; ++c) cw[c] = conv_w[lane*6 + c];
    int pa_ = 0, pb_ = 0;
    if (lane >= 6 && lane < 27) {
        int t = lane - 6, a = 0;
        while (t >= 6 - a) { t -= 6 - a; ++a; }
        pa_ = a; pb_ = a + t;
    }
    double acc = 0.0;
    for (int i = 0; i < 8; ++i) {
        const int bp = blockIdx.x * 32 + wv * 8 + i;
        const int b = bp >> 11, n = bp & (NPTS - 1);
        const float* xb = x + (size_t)b * NPTS * 3;
        const float xi0 = xb[n*3+0], xi1 = xb[n*3+1], xi2 = xb[n*3+2];
        float f0=0,f1=0,f2=0,f3=0,f4=0,f5=0;
        if (lane < KNBR) {
            const int nj = idx[(size_t)bp * KNBR + lane];
            f0 = xb[nj*3+0] - xi0; f1 = xb[nj*3+1] - xi1; f2 = xb[nj*3+2] - xi2;
            f3 = xi0; f4 = xi1; f5 = xi2;
        }
        __syncthreads();
        if (lane < KNBR) {
            featw[wv][lane][0]=f0; featw[wv][lane][1]=f1; featw[wv][lane][2]=f2;
            featw[wv][lane][3]=f3; featw[wv][lane][4]=f4; featw[wv][lane][5]=f5;
        }
        __syncthreads();
        float vmax = -__builtin_inff(), vmin = __builtin_inff();
#pragma unroll
        for (int k = 0; k < KNBR; ++k) {
            float h = featw[wv][k][0] * cw[0];
            h = fmaf(featw[wv][k][1], cw[1], h);
            h = fmaf(featw[wv][k][2], cw[2], h);
            h = fmaf(featw[wv][k][3], cw[3], h);
            h = fmaf(featw[wv][k][4], cw[4], h);
            h = fmaf(featw[wv][k][5], cw[5], h);
            vmax = fmaxf(vmax, h); vmin = fminf(vmin, h);
        }
        maxh[(size_t)bp*64 + lane] = vmax;
        minh[(size_t)bp*64 + lane] = vmin;
        if (lane < 6) {
            double s = 0;
#pragma unroll
            for (int k = 0; k < KNBR; ++k) s += (double)featw[wv][k][lane];
            acc += s;
        } else if (lane < 27) {
            double s = 0;
#pragma unroll
            for (int k = 0; k < KNBR; ++k)
                s += (double)featw[wv][k][pa_] * (double)featw[wv][k][pb_];
            acc += s;
        }
    }
    if (lane < 27) sred[wv][lane] = acc;
    __syncthreads();
    if (threadIdx.x < 27) {
        double tot = sred[0][threadIdx.x] + sred[1][threadIdx.x]
                   + sred[2][threadIdx.x] + sred[3][threadIdx.x];
        atomicAdd(&S[threadIdx.x], tot);
    }
}

__global__ void stats0_kernel(const double* __restrict__ S, const float* __restrict__ conv_w,
        const float* __restrict__ g, const float* __restrict__ bb,
        float* __restrict__ scale, float* __restrict__ shift)
{
    const int o = threadIdx.x;
    double w[6];
#pragma unroll
    for (int c = 0; c < 6; ++c) w[c] = (double)conv_w[o*6 + c];
    double mean = 0.0;
#pragma unroll
    for (int c = 0; c < 6; ++c) mean += w[c] * S[c];
    mean /= CONV_M;
    double ey2 = 0.0;
    int t = 6;
#pragma unroll
    for (int a = 0; a < 6; ++a)
#pragma unroll
        for (int b2 = a; b2 < 6; ++b2) {
            double coef = (a == b2) ? 1.0 : 2.0;
            ey2 += coef * w[a] * w[b2] * S[t];
            ++t;
        }
    ey2 /= CONV_M;
    double var = ey2 - mean * mean;
    double sc = (double)g[o] / sqrt(var + BN_EPS);
    scale[o] = (float)sc;
    shift[o] = (float)((double)bb[o] - mean * sc);
}

__global__ void statsL_kernel(const double* __restrict__ sum, const double* __restrict__ sq,
        const float* __restrict__ g, const float* __restrict__ bt,
        float* __restrict__ scale, float* __restrict__ shift, int C)
{
    const int o = threadIdx.x;
    if (o >= C) return;
    double m = sum[o] / ROW_M;
    double v = sq[o] / ROW_M - m * m;
    double sc = (double)g[o] / sqrt(v + BN_EPS);
    scale[o] = (float)sc;
    shift[o] = (float)((double)bt[o] - m * sc);
}

// ---------------------------------------------------------------------------
// MLP GEMM: BM=64 rows/block, full N, BK=64 (restage for K=128).
// A staged transposed [k][row] with XOR swizzle (conflict-free b128 reads),
// BN+lrelu fused into staging; column stats fused into epilogue.
// FMA order per output: bias, then k ascending (bit-identical to prior).
// ---------------------------------------------------------------------------
template<int K, int N, bool SEL>
__global__ __launch_bounds__(256) void mlp_gemm(const float* __restrict__ A,
        const float* __restrict__ A2, const float* __restrict__ sc_,
        const float* __restrict__ sh_, const float* __restrict__ W,
        const float* __restrict__ bias, float* __restrict__ Y,
        double* __restrict__ sum, double* __restrict__ sq)
{
    constexpr int CPT = N / 16;                 // cols per thread (4 or 8)
    __shared__ float As[64 * 64];               // [k][row^swz], 16 KB
    __shared__ float Ws[64 * N];                // [k][n], 16/32 KB
    const int tid = threadIdx.x;
    const int row0 = blockIdx.x * 64;
    const int ct = tid & 15, rt = tid >> 4;     // col-group, row-group
    float acc[4][CPT];
#pragma unroll
    for (int rr = 0; rr < 4; ++rr)
#pragma unroll
        for (int cc = 0; cc < CPT; ++cc) acc[rr][cc] = bias[ct*CPT + cc];

    for (int kk = 0; kk < K/64; ++kk) {
        if (kk) __syncthreads();
        // stage A (transposed + swizzled), activation fused
#pragma unroll
        for (int i = 0; i < 4; ++i) {
            const int f   = i * 256 + tid;      // float4 tile index
            const int k4  = f & 15;
            const int row = f >> 4;
            const int kg  = kk*64 + k4*4;
            float4 m = *(const float4*)(A + (size_t)(row0+row)*K + kg);
            const float4 s4 = *(const float4*)(sc_ + kg);
            const float4 h4 = *(const float4*)(sh_ + kg);
            if (SEL) {
                float4 m2 = *(const float4*)(A2 + (size_t)(row0+row)*K + kg);
                m.x = s4.x >= 0.f ? m.x : m2.x;
                m.y = s4.y >= 0.f ? m.y : m2.y;
                m.z = s4.z >= 0.f ? m.z : m2.z;
                m.w = s4.w >= 0.f ? m.w : m2.w;
            }
            const int rsw = row ^ ((k4 & 7) << 2);   // ((k>>2)&7)<<2 with k=k4*4+j
            As[(k4*4+0)*64 + rsw] = lrelu(fmaf(s4.x, m.x, h4.x));
            As[(k4*4+1)*64 + rsw] = lrelu(fmaf(s4.y, m.y, h4.y));
            As[(k4*4+2)*64 + rsw] = lrelu(fmaf(s4.z, m.z, h4.z));
            As[(k4*4+3)*64 + rsw] = lrelu(fmaf(s4.w, m.w, h4.w));
        }
        // stage W
#pragma unroll
        for (int i = 0; i < N/16; ++i) {
            const int f    = i * 256 + tid;     // float4 index into 64 x N/4
            const int col4 = f & (N/4 - 1);
            const int krow = f / (N/4);
            *(float4*)(&Ws[krow*N + col4*4]) =
                *(const float4*)(W + (size_t)(kk*64 + krow)*N + col4*4);
        }
        __syncthreads();
#pragma unroll 4
        for (int k = 0; k < 64; ++k) {
            const int sw = ((k >> 2) & 7) << 2;
            const float4 a0 = *(const float4*)(&As[k*64 + ((rt*4) ^ sw)]);
            float a_[4] = {a0.x, a0.y, a0.z, a0.w};
            float w_[CPT];
#pragma unroll
            for (int v = 0; v < CPT/4; ++v) {
                const float4 wv4 = *(const float4*)(&Ws[k*N + ct*CPT + v*4]);
                w_[v*4+0] = wv4.x; w_[v*4+1] = wv4.y; w_[v*4+2] = wv4.z; w_[v*4+3] = wv4.w;
            }
#pragma unroll
            for (int rr = 0; rr < 4; ++rr)
#pragma unroll
                for (int cc = 0; cc < CPT; ++cc)
                    acc[rr][cc] = fmaf(a_[rr], w_[cc], acc[rr][cc]);
        }
    }
    // store + fused column stats
#pragma unroll
    for (int rr = 0; rr < 4; ++rr) {
        float* yo = Y + (size_t)(row0 + rt*4 + rr)*N + ct*CPT;
#pragma unroll
        for (int v = 0; v < CPT/4; ++v)
            *(float4*)(yo + v*4) = make_float4(acc[rr][v*4+0], acc[rr][v*4+1],
                                               acc[rr][v*4+2], acc[rr][v*4+3]);
    }
    __syncthreads();                  // As dead, reuse as colred[2][N]
    float* cr = As;
    if (tid < 2*N) cr[tid] = 0.f;
    __syncthreads();
#pragma unroll
    for (int cc = 0; cc < CPT; ++cc) {
        float s = acc[0][cc] + acc[1][cc] + acc[2][cc] + acc[3][cc];
        float q = fmaf(acc[0][cc], acc[0][cc], 0.f);
        q = fmaf(acc[1][cc], acc[1][cc], q);
        q = fmaf(acc[2][cc], acc[2][cc], q);
        q = fmaf(acc[3][cc], acc[3][cc], q);
        atomicAdd(&cr[ct*CPT + cc], s);
        atomicAdd(&cr[N + ct*CPT + cc], q);
    }
    __syncthreads();
    if (tid < N) {
        atomicAdd(&sum[tid], (double)cr[tid]);
        atomicAdd(&sq[tid],  (double)cr[N + tid]);
    }
}

// pool stage 1: max over 128-point slab with BN+lrelu inline
__global__ __launch_bounds__(256) void pool1_kernel(const float* __restrict__ y3,
        const float* __restrict__ s3, const float* __restrict__ t3, float* __restrict__ pp)
{
    const int b = blockIdx.x >> 4, ns = blockIdx.x & 15;
    const int wv = threadIdx.x >> 6, lane = threadIdx.x & 63;
    const int ch = (wv & 1) * 64 + lane;
    const float sc = s3[ch], sh = t3[ch];
    float m = -__builtin_inff();
    const int n0 = ns * 128 + (wv >> 1) * 64;
    for (int n = n0; n < n0 + 64; ++n) {
        float v = lrelu(fmaf(sc, y3[((size_t)b*NPTS + n)*128 + ch], sh));
        m = fmaxf(m, v);
    }
    __shared__ float red[2][128];
    red[wv >> 1][ch] = m;
    __syncthreads();
    if (threadIdx.x < 128)
        pp[((size_t)b*16 + ns)*128 + threadIdx.x] = fmaxf(red[0][threadIdx.x], red[1][threadIdx.x]);
}

__global__ void pool2_kernel(const float* __restrict__ pp, float* __restrict__ pooled)
{
    const int b = blockIdx.x, ch = threadIdx.x;
    float m = -__builtin_inff();
    for (int ns = 0; ns < 16; ++ns)
        m = fmaxf(m, pp[((size_t)b*16 + ns)*128 + ch]);
    pooled[b*128 + ch] = m;
}

__global__ __launch_bounds__(256) void head_kernel(const float* __restrict__ pooled,
        const float* __restrict__ w4, const float* __restrict__ b4,
        const float* __restrict__ w5, const float* __restrict__ b5, float* __restrict__ out)
{
    __shared__ float xr[128];
    __shared__ float hh[512];
    const int b = blockIdx.x, t = threadIdx.x;
    if (t < 128) xr[t] = pooled[b*128 + t];
    __syncthreads();
    float h0 = b4[t], h1 = b4[t + 256];
    for (int c = 0; c < 128; ++c) {
        float xc = xr[c];
        h0 = fmaf(xc, w4[c*512 + t],       h0);
        h1 = fmaf(xc, w4[c*512 + t + 256], h1);
    }
    hh[t]       = lrelu(h0);
    hh[t + 256] = lrelu(h1);
    __syncthreads();
    float acc = b5[t];
    for (int c = 0; c < 512; ++c)
        acc = fmaf(hh[c], w5[c*256 + t], acc);
    out[b*256 + t] = acc;
}

extern "C" void kernel_launch(void* const* d_in, const int* in_sizes, int n_in,
                              void* d_out, int out_size, void* d_ws, size_t ws_size,
                              hipStream_t stream)
{
    const float* x      = (const float*)d_in[0];
    const float* conv_w = (const float*)d_in[1];
    const float* conv_g = (const float*)d_in[2];
    const float* conv_b = (const float*)d_in[3];
    const float* w1  = (const float*)d_in[4];
    const float* b1  = (const float*)d_in[5];
    const float* g1  = (const float*)d_in[6];
    const float* bt1 = (const float*)d_in[7];
    const float* w2  = (const float*)d_in[8];
    const float* b2  = (const float*)d_in[9];
    const float* g2  = (const float*)d_in[10];
    const float* bt2 = (const float*)d_in[11];
    const float* w3  = (const float*)d_in[12];
    const float* b3  = (const float*)d_in[13];
    const float* g3  = (const float*)d_in[14];
    const float* bt3 = (const float*)d_in[15];
    const float* w4  = (const float*)d_in[16];
    const float* b4  = (const float*)d_in[17];
    const float* w5  = (const float*)d_in[18];
    const float* b5  = (const float*)d_in[19];

    char* p = (char*)d_ws;
    auto take = [&](size_t bytes) -> char* {
        char* r = p; p += (bytes + 255) & ~(size_t)255; return r;
    };
    double* S    = (double*)take(27 * 8);
    double* sum1 = (double*)take(64 * 8);
    double* sq1  = (double*)take(64 * 8);
    double* sum2 = (double*)take(128 * 8);
    double* sq2  = (double*)take(128 * 8);
    double* sum3 = (double*)take(128 * 8);
    double* sq3  = (double*)take(128 * 8);
    size_t zero_bytes = (size_t)(p - (char*)d_ws);
    float* scale0 = (float*)take(64 * 4);
    float* shift0 = (float*)take(64 * 4);
    float* scale1 = (float*)take(64 * 4);
    float* shift1 = (float*)take(64 * 4);
    float* scale2 = (float*)take(128 * 4);
    float* shift2 = (float*)take(128 * 4);
    float* scale3 = (float*)take(128 * 4);
    float* shift3 = (float*)take(128 * 4);
    float* pooled = (float*)take(NB * 128 * 4);
    float* pp     = (float*)take((size_t)NB * 16 * 128 * 4);
    float* thresh = (float*)take((size_t)NROWS * 4);
    int*   idx    = (int*)take((size_t)NROWS * KNBR * 4);
    float* mm     = (float*)take((size_t)NROWS * 128 * 4);   // 16 MB
    float* maxh   = mm;
    float* minh   = mm + (size_t)NROWS * 64;
    float* y1     = (float*)take((size_t)NROWS * 64 * 4);    // 8 MB
    float* y2     = (float*)take((size_t)NROWS * 128 * 4);   // 16 MB
    float* y3     = mm;   // alias (maxh/minh dead after mlp1)
    float* P      = mm;   // alias: knn partials 16*20*NROWS*4 = 41.94 MB over mm+y1+y2 (all dead here)

    hipMemsetAsync(d_ws, 0, zero_bytes, stream);
    knn_part  <<<dim3(NB * 8 * NCH), dim3(256), 0, stream>>>(x, P);
    knn_merge <<<dim3(NROWS / 256),  dim3(256), 0, stream>>>(P, thresh);
    knn_idx   <<<dim3(NB * 64),      dim3(256), 0, stream>>>(x, thresh, idx);
    feat_kernel <<<dim3(NROWS / 32), dim3(256), 0, stream>>>(x, idx, conv_w, maxh, minh, S);
    stats0_kernel<<<dim3(1),         dim3(64),  0, stream>>>(S, conv_w, conv_g, conv_b, scale0, shift0);

    mlp_gemm<64,64,true>   <<<dim3(512), dim3(256), 0, stream>>>(maxh, minh, scale0, shift0, w1, b1, y1, sum1, sq1);
    statsL_kernel          <<<dim3(1),   dim3(64),  0, stream>>>(sum1, sq1, g1, bt1, scale1, shift1, 64);
    mlp_gemm<64,128,false> <<<dim3(512), dim3(256), 0, stream>>>(y1, y1, scale1, shift1, w2, b2, y2, sum2, sq2);
    statsL_kernel          <<<dim3(1),   dim3(128), 0, stream>>>(sum2, sq2, g2, bt2, scale2, shift2, 128);
    mlp_gemm<128,128,false><<<dim3(512), dim3(256), 0, stream>>>(y2, y2, scale2, shift2, w3, b3, y3, sum3, sq3);
    statsL_kernel          <<<dim3(1),   dim3(128), 0, stream>>>(sum3, sq3, g3, bt3, scale3, shift3, 128);

    pool1_kernel<<<dim3(NB * 16),    dim3(256), 0, stream>>>(y3, scale3, shift3, pp);
    pool2_kernel<<<dim3(NB),         dim3(128), 0, stream>>>(pp, pooled);
    head_kernel <<<dim3(NB),         dim3(256), 0, stream>>>(pooled, w4, b4, w5, b5, (float*)d_out);
}